// Round 5
// baseline (480.933 us; speedup 1.0000x reference)
//
#include <hip/hip_runtime.h>
#include <cstddef>
#include <cstdint>

#define D_MODEL 512
#define DK 64
#define LQ 1024
#define LK 1024
#define NB 2
#define LN_EPS 1e-6f
#define L2E2 2.8853900817779268f  // 2*log2(e)

// pack two floats to bf16x2 (RNE), low word = a
__device__ __forceinline__ uint32_t pack_bf2(float a, float b) {
  uint32_t ua = __float_as_uint(a), ub = __float_as_uint(b);
  ua = (ua + 0x7fffu + ((ua >> 16) & 1u)) >> 16;
  ub = (ub + 0x7fffu + ((ub >> 16) & 1u)) >> 16;
  return (ub << 16) | ua;
}

// ---------------- projections ----------------
// type 0: qp=q@Wq -> ab_g[row][d] = {v_d*e^{-2qp}, e^{-2qp}}
// type 1: ek=e^{2*(k@Wk)} -> ekT[batch][dp][j] u32 = bf16{ek[dp], ek[dp+32]}
//         (dp-major transpose: attn reads it fully coalesced per dp)
// type 2: vp = v@Wv (f32 row-major)
// 512 thr (8 waves), 16 rows/block, 2 rows/wave, lane = output col d.
// Rows staged in LDS (float4 coalesced, read as b128 broadcast);
// W read per-lane from global (256B/wave-instr, L2-resident).
#define PR_ROWS 16
__global__ __launch_bounds__(512) void proj_kernel(
    const float* __restrict__ q, const float* __restrict__ k,
    const float* __restrict__ v, const float* __restrict__ Wq,
    const float* __restrict__ Wk, const float* __restrict__ Wv,
    const float* __restrict__ v_param, float2* __restrict__ ab_g,
    uint32_t* __restrict__ ekT, float* __restrict__ vp) {
  __shared__ float rows[PR_ROWS][D_MODEL];
  const int tid = threadIdx.x;
  const int type = blockIdx.x >> 7;  // 128 row-groups per type
  const int r0 = (blockIdx.x & 127) * PR_ROWS;
  const float* __restrict__ in = (type == 0) ? q : (type == 1) ? k : v;
  const float* __restrict__ W = (type == 0) ? Wq : (type == 1) ? Wk : Wv;
  {
    const float4* __restrict__ in4 = (const float4*)(in + (size_t)r0 * D_MODEL);
    float4* r4 = (float4*)&rows[0][0];
#pragma unroll
    for (int t = 0; t < 4; ++t) r4[tid + 512 * t] = in4[tid + 512 * t];
  }
  __syncthreads();
  const int lane = tid & 63;
  const int wv = tid >> 6;           // 0..7
  const int rglob = r0 + wv * 2;     // this wave's first global row
  const float* __restrict__ rA = rows[wv * 2];
  const float* __restrict__ rB = rows[wv * 2 + 1];
  float a00 = 0.f, a01 = 0.f, a10 = 0.f, a11 = 0.f;  // 2 chains per row
#pragma unroll 4
  for (int e = 0; e < D_MODEL; e += 4) {
    float w0 = W[(size_t)(e + 0) * DK + lane];
    float w1 = W[(size_t)(e + 1) * DK + lane];
    float w2 = W[(size_t)(e + 2) * DK + lane];
    float w3 = W[(size_t)(e + 3) * DK + lane];
    float4 a4 = *(const float4*)&rA[e];
    float4 b4 = *(const float4*)&rB[e];
    a00 = fmaf(a4.x, w0, a00); a01 = fmaf(a4.y, w1, a01);
    a00 = fmaf(a4.z, w2, a00); a01 = fmaf(a4.w, w3, a01);
    a10 = fmaf(b4.x, w0, a10); a11 = fmaf(b4.y, w1, a11);
    a10 = fmaf(b4.z, w2, a10); a11 = fmaf(b4.w, w3, a11);
  }
  float acc0 = a00 + a01, acc1 = a10 + a11;
  if (type == 0) {
    float vpar = v_param[lane];
    float i0 = __builtin_amdgcn_exp2f(-L2E2 * acc0);
    float i1 = __builtin_amdgcn_exp2f(-L2E2 * acc1);
    ab_g[(size_t)(rglob + 0) * DK + lane] = make_float2(vpar * i0, i0);
    ab_g[(size_t)(rglob + 1) * DK + lane] = make_float2(vpar * i1, i1);
  } else if (type == 1) {
    float e0 = __builtin_amdgcn_exp2f(L2E2 * acc0);
    float e1 = __builtin_amdgcn_exp2f(L2E2 * acc1);
    float h0 = __shfl_down(e0, 32);  // lane d gets Ek[d+32]
    float h1 = __shfl_down(e1, 32);
    if (lane < 32) {
      int b0 = (rglob) >> 10, j0 = (rglob)&1023;
      int b1 = (rglob + 1) >> 10, j1 = (rglob + 1) & 1023;
      ekT[(size_t)b0 * 32 * LK + (size_t)lane * LK + j0] = pack_bf2(e0, h0);
      ekT[(size_t)b1 * 32 * LK + (size_t)lane * LK + j1] = pack_bf2(e1, h1);
    }
  } else {
    vp[(size_t)(rglob + 0) * DK + lane] = acc0;
    vp[(size_t)(rglob + 1) * DK + lane] = acc1;
  }
}

// ---------------- fused scores + softmax + PV + FC + LN ----------------
// 256 thr (4 waves), RB=4 rows/block, grid 512. Thread owns j = jt*256+tid.
// K data read straight from L2-resident ekT: per dp one coalesced dword load
// per wave. A/B per row via fp32 LDS float4 broadcasts. NO k staging, NO
// barriers in the score loop.
#define RB 4
__global__ __launch_bounds__(256) void attn_kernel(
    const float2* __restrict__ ab_g, const uint32_t* __restrict__ ekT,
    const float* __restrict__ vp, const float* __restrict__ resid,
    const float* __restrict__ Wfc, const float* __restrict__ gamma,
    const float* __restrict__ beta, float* __restrict__ out,
    float* __restrict__ attn_out) {
  __shared__ float sc[RB][LK];         // 16 KB scores -> probs
  __shared__ float4 ab4s[RB][32];      // {A_dp,B_dp,A_dp+32,B_dp+32}
  __shared__ float4 pvred[4][RB][16];  // PV cross-wave partials
  __shared__ float ovl[RB][DK];        // attention output rows
  __shared__ float red[2][RB][4];      // LN reductions
  const int tid = threadIdx.x;
  const int row0 = blockIdx.x * RB;
  const int batch = row0 >> 10;
  const uint32_t* __restrict__ ekT_b = ekT + (size_t)batch * 32 * LK;
  const float* __restrict__ vp_b = vp + (size_t)batch * LK * DK;

  {
    int r = tid >> 6, d = tid & 63;
    float2 abv = ab_g[(size_t)(row0 + r) * DK + d];
    ((float2*)&ab4s[r][d & 31])[d >> 5] = abv;
  }
  __syncthreads();

  // -------- scores: score_j = C - 2*acc_j (C constant, drops in softmax)
#pragma unroll
  for (int jt = 0; jt < LK / 256; ++jt) {
    const int j = (jt << 8) + tid;
    float a0 = 0.f, a1 = 0.f, a2 = 0.f, a3 = 0.f;
#pragma unroll
    for (int dp = 0; dp < 32; ++dp) {
      uint32_t kw = ekT_b[(size_t)dp * LK + j];
      float klo = __uint_as_float(kw << 16);
      float khi = __uint_as_float(kw & 0xffff0000u);
      {
        float4 ab = ab4s[0][dp];
        float x1 = klo + ab.y, x2 = khi + ab.w;
        float num = fmaf(ab.z, x1, ab.x * x2);
        a0 = fmaf(num, __builtin_amdgcn_rcpf(x1 * x2), a0);
      }
      {
        float4 ab = ab4s[1][dp];
        float x1 = klo + ab.y, x2 = khi + ab.w;
        float num = fmaf(ab.z, x1, ab.x * x2);
        a1 = fmaf(num, __builtin_amdgcn_rcpf(x1 * x2), a1);
      }
      {
        float4 ab = ab4s[2][dp];
        float x1 = klo + ab.y, x2 = khi + ab.w;
        float num = fmaf(ab.z, x1, ab.x * x2);
        a2 = fmaf(num, __builtin_amdgcn_rcpf(x1 * x2), a2);
      }
      {
        float4 ab = ab4s[3][dp];
        float x1 = klo + ab.y, x2 = khi + ab.w;
        float num = fmaf(ab.z, x1, ab.x * x2);
        a3 = fmaf(num, __builtin_amdgcn_rcpf(x1 * x2), a3);
      }
    }
    sc[0][j] = a0; sc[1][j] = a1; sc[2][j] = a2; sc[3][j] = a3;
  }
  __syncthreads();

  const int wvv = __builtin_amdgcn_readfirstlane(tid >> 6);
  const int lane = tid & 63;

  // -------- softmax over score = C - 2*acc -> shift by min(acc); wave = row
  {
    const int r = wvv;
    float m = 1e30f;
#pragma unroll
    for (int i = 0; i < 16; ++i) m = fminf(m, sc[r][i * 64 + lane]);
#pragma unroll
    for (int off = 32; off > 0; off >>= 1) m = fminf(m, __shfl_xor(m, off));
    float p[16];
    float ssum = 0.f;
#pragma unroll
    for (int i = 0; i < 16; ++i) {
      float e = __builtin_amdgcn_exp2f((m - sc[r][i * 64 + lane]) * L2E2);
      p[i] = e;
      ssum += e;
    }
#pragma unroll
    for (int off = 32; off > 0; off >>= 1) ssum += __shfl_xor(ssum, off);
    float inv = __builtin_amdgcn_rcpf(ssum);
    float* __restrict__ arow = attn_out + (size_t)(row0 + r) * LK;
#pragma unroll
    for (int i = 0; i < 16; ++i) {
      float pn = p[i] * inv;
      sc[r][i * 64 + lane] = pn;  // keep for PV
      arow[i * 64 + lane] = pn;
    }
  }
  __syncthreads();

  // -------- PV: wave owns 256-j slice; vp read once per block per j
  {
    const int jj = lane >> 4, l16 = lane & 15;
    const float4* __restrict__ vp4 = (const float4*)vp_b;
    float4 a[RB];
#pragma unroll
    for (int r = 0; r < RB; ++r) a[r] = make_float4(0.f, 0.f, 0.f, 0.f);
#pragma unroll 4
    for (int it = 0; it < 64; ++it) {
      int j = (wvv << 8) + (it << 2) + jj;
      float4 vv = vp4[(size_t)j * (DK / 4) + l16];
#pragma unroll
      for (int r = 0; r < RB; ++r) {
        float pw = sc[r][j];
        a[r].x = fmaf(pw, vv.x, a[r].x);
        a[r].y = fmaf(pw, vv.y, a[r].y);
        a[r].z = fmaf(pw, vv.z, a[r].z);
        a[r].w = fmaf(pw, vv.w, a[r].w);
      }
    }
#pragma unroll
    for (int r = 0; r < RB; ++r) {
      a[r].x += __shfl_xor(a[r].x, 16); a[r].y += __shfl_xor(a[r].y, 16);
      a[r].z += __shfl_xor(a[r].z, 16); a[r].w += __shfl_xor(a[r].w, 16);
      a[r].x += __shfl_xor(a[r].x, 32); a[r].y += __shfl_xor(a[r].y, 32);
      a[r].z += __shfl_xor(a[r].z, 32); a[r].w += __shfl_xor(a[r].w, 32);
    }
    if (jj == 0) {
#pragma unroll
      for (int r = 0; r < RB; ++r) pvred[wvv][r][l16] = a[r];
    }
  }
  __syncthreads();
  if (tid < 64) {
    int r = tid >> 4, l16 = tid & 15;
    float4 s = make_float4(0.f, 0.f, 0.f, 0.f);
#pragma unroll
    for (int w = 0; w < 4; ++w) {
      float4 t = pvred[w][r][l16];
      s.x += t.x; s.y += t.y; s.z += t.z; s.w += t.w;
    }
    ((float4*)ovl[r])[l16] = s;
  }
  __syncthreads();

  // -------- FC + residual + LayerNorm tail (rows stay in LDS)
  {
    const int c0 = tid, c1 = tid + 256;
    float y[RB][2];
#pragma unroll
    for (int r = 0; r < RB; ++r) {
      y[r][0] = resid[(size_t)(row0 + r) * D_MODEL + c0];
      y[r][1] = resid[(size_t)(row0 + r) * D_MODEL + c1];
    }
#pragma unroll 4
    for (int e = 0; e < DK; ++e) {
      float w0 = Wfc[(size_t)e * D_MODEL + c0];
      float w1 = Wfc[(size_t)e * D_MODEL + c1];
#pragma unroll
      for (int r = 0; r < RB; ++r) {
        float o = ovl[r][e];
        y[r][0] = fmaf(o, w0, y[r][0]);
        y[r][1] = fmaf(o, w1, y[r][1]);
      }
    }
#pragma unroll
    for (int r = 0; r < RB; ++r) {
      float s = y[r][0] + y[r][1];
#pragma unroll
      for (int off = 32; off > 0; off >>= 1) s += __shfl_xor(s, off);
      if (lane == 0) red[0][r][wvv] = s;
    }
    __syncthreads();
    float mu[RB];
#pragma unroll
    for (int r = 0; r < RB; ++r)
      mu[r] = (red[0][r][0] + red[0][r][1] + red[0][r][2] + red[0][r][3]) *
              (1.0f / D_MODEL);
#pragma unroll
    for (int r = 0; r < RB; ++r) {
      float d0 = y[r][0] - mu[r], d1 = y[r][1] - mu[r];
      float s = d0 * d0 + d1 * d1;
#pragma unroll
      for (int off = 32; off > 0; off >>= 1) s += __shfl_xor(s, off);
      if (lane == 0) red[1][r][wvv] = s;
    }
    __syncthreads();
    float g0 = gamma[c0], g1 = gamma[c1], b0 = beta[c0], b1 = beta[c1];
#pragma unroll
    for (int r = 0; r < RB; ++r) {
      float var = (red[1][r][0] + red[1][r][1] + red[1][r][2] + red[1][r][3]) *
                  (1.0f / D_MODEL);
      float rstd = rsqrtf(var + LN_EPS);
      out[(size_t)(row0 + r) * D_MODEL + c0] = (y[r][0] - mu[r]) * rstd * g0 + b0;
      out[(size_t)(row0 + r) * D_MODEL + c1] = (y[r][1] - mu[r]) * rstd * g1 + b1;
    }
  }
}

extern "C" void kernel_launch(void* const* d_in, const int* in_sizes, int n_in,
                              void* d_out, int out_size, void* d_ws,
                              size_t ws_size, hipStream_t stream) {
  const float* q = (const float*)d_in[0];
  const float* k = (const float*)d_in[1];
  const float* v = (const float*)d_in[2];
  const float* Wq = (const float*)d_in[3];
  const float* Wk = (const float*)d_in[4];
  const float* Wv = (const float*)d_in[5];
  const float* v_param = (const float*)d_in[6];
  const float* Wfc = (const float*)d_in[7];
  const float* gamma = (const float*)d_in[8];
  const float* beta = (const float*)d_in[9];

  float* out = (float*)d_out;                     // [B*LQ*D_MODEL]
  float* attn = out + (size_t)NB * LQ * D_MODEL;  // [B*LQ*LK]

  float* base = (float*)d_ws;
  float2* ab_g = (float2*)base;                      // [2048*64] float2
  uint32_t* ekT = (uint32_t*)(base + (size_t)2 * NB * LQ * DK);  // [2*32*1024]
  float* vp = base + (size_t)2 * NB * LQ * DK + NB * 32 * LK;    // [2048*64]

  hipLaunchKernelGGL(proj_kernel, dim3(3 * 128), dim3(512), 0, stream, q, k, v,
                     Wq, Wk, Wv, v_param, ab_g, ekT, vp);
  hipLaunchKernelGGL(attn_kernel, dim3(NB * LQ / RB), dim3(256), 0, stream,
                     ab_g, ekT, vp, q, Wfc, gamma, beta, out, attn);
}

// Round 6
// 147.869 us; speedup vs baseline: 3.2524x; 3.2524x over previous
//
#include <hip/hip_runtime.h>
#include <cstddef>
#include <cstdint>

#define D_MODEL 512
#define DK 64
#define LQ 1024
#define LK 1024
#define NB 2
#define LN_EPS 1e-6f
#define L2E2 2.8853900817779268f  // 2*log2(e)

// pack two floats to bf16x2 (RNE), low word = a
__device__ __forceinline__ uint32_t pack_bf2(float a, float b) {
  uint32_t ua = __float_as_uint(a), ub = __float_as_uint(b);
  ua = (ua + 0x7fffu + ((ua >> 16) & 1u)) >> 16;
  ub = (ub + 0x7fffu + ((ub >> 16) & 1u)) >> 16;
  return (ub << 16) | ua;
}

// ---------------- projections ----------------
// type 0: qp=q@Wq -> ab_g[row][d] = {v_d*e^{-2qp}, e^{-2qp}}
// type 1: ek=e^{2*(k@Wk)} -> ekT[batch][dp][j] u32 = bf16{ek[dp], ek[dp+32]}
// type 2: vp = v@Wv (f32 row-major)
// 512 thr (8 waves), 16 rows/block, 2 rows/wave, lane = output col d.
#define PR_ROWS 16
__global__ __launch_bounds__(512) void proj_kernel(
    const float* __restrict__ q, const float* __restrict__ k,
    const float* __restrict__ v, const float* __restrict__ Wq,
    const float* __restrict__ Wk, const float* __restrict__ Wv,
    const float* __restrict__ v_param, float2* __restrict__ ab_g,
    uint32_t* __restrict__ ekT, float* __restrict__ vp) {
  __shared__ float rows[PR_ROWS][D_MODEL];
  const int tid = threadIdx.x;
  const int type = blockIdx.x >> 7;  // 128 row-groups per type
  const int r0 = (blockIdx.x & 127) * PR_ROWS;
  const float* __restrict__ in = (type == 0) ? q : (type == 1) ? k : v;
  const float* __restrict__ W = (type == 0) ? Wq : (type == 1) ? Wk : Wv;
  {
    const float4* __restrict__ in4 = (const float4*)(in + (size_t)r0 * D_MODEL);
    float4* r4 = (float4*)&rows[0][0];
#pragma unroll
    for (int t = 0; t < 4; ++t) r4[tid + 512 * t] = in4[tid + 512 * t];
  }
  __syncthreads();
  const int lane = tid & 63;
  const int wv = tid >> 6;           // 0..7
  const int rglob = r0 + wv * 2;     // this wave's first global row
  const float* __restrict__ rA = rows[wv * 2];
  const float* __restrict__ rB = rows[wv * 2 + 1];
  float a00 = 0.f, a01 = 0.f, a10 = 0.f, a11 = 0.f;  // 2 chains per row
#pragma unroll 4
  for (int e = 0; e < D_MODEL; e += 4) {
    float w0 = W[(size_t)(e + 0) * DK + lane];
    float w1 = W[(size_t)(e + 1) * DK + lane];
    float w2 = W[(size_t)(e + 2) * DK + lane];
    float w3 = W[(size_t)(e + 3) * DK + lane];
    float4 a4 = *(const float4*)&rA[e];
    float4 b4 = *(const float4*)&rB[e];
    a00 = fmaf(a4.x, w0, a00); a01 = fmaf(a4.y, w1, a01);
    a00 = fmaf(a4.z, w2, a00); a01 = fmaf(a4.w, w3, a01);
    a10 = fmaf(b4.x, w0, a10); a11 = fmaf(b4.y, w1, a11);
    a10 = fmaf(b4.z, w2, a10); a11 = fmaf(b4.w, w3, a11);
  }
  float acc0 = a00 + a01, acc1 = a10 + a11;
  if (type == 0) {
    float vpar = v_param[lane];
    float i0 = __builtin_amdgcn_exp2f(-L2E2 * acc0);
    float i1 = __builtin_amdgcn_exp2f(-L2E2 * acc1);
    ab_g[(size_t)(rglob + 0) * DK + lane] = make_float2(vpar * i0, i0);
    ab_g[(size_t)(rglob + 1) * DK + lane] = make_float2(vpar * i1, i1);
  } else if (type == 1) {
    float e0 = __builtin_amdgcn_exp2f(L2E2 * acc0);
    float e1 = __builtin_amdgcn_exp2f(L2E2 * acc1);
    float h0 = __shfl_down(e0, 32);  // lane d gets Ek[d+32]
    float h1 = __shfl_down(e1, 32);
    if (lane < 32) {
      int b0 = (rglob) >> 10, j0 = (rglob)&1023;
      int b1 = (rglob + 1) >> 10, j1 = (rglob + 1) & 1023;
      ekT[(size_t)b0 * 32 * LK + (size_t)lane * LK + j0] = pack_bf2(e0, h0);
      ekT[(size_t)b1 * 32 * LK + (size_t)lane * LK + j1] = pack_bf2(e1, h1);
    }
  } else {
    vp[(size_t)(rglob + 0) * DK + lane] = acc0;
    vp[(size_t)(rglob + 1) * DK + lane] = acc1;
  }
}

// ---------------- fused scores + softmax + PV + FC + LN ----------------
// 256 thr (4 waves), RB=4 rows/block, grid 512 (XCD-swizzled). Thread owns
// j = jt*256+tid. K read straight from L2-resident ekT (coalesced dword per
// dp). launch_bounds(256,4) caps VGPR at 128 -- NO spill (round-5 lesson);
// jt loop kept rolled so only one tile's 32 loads are in flight.
#define RB 4
__global__ __launch_bounds__(256, 4) void attn_kernel(
    const float2* __restrict__ ab_g, const uint32_t* __restrict__ ekT,
    const float* __restrict__ vp, const float* __restrict__ resid,
    const float* __restrict__ Wfc, const float* __restrict__ gamma,
    const float* __restrict__ beta, float* __restrict__ out,
    float* __restrict__ attn_out) {
  __shared__ float sc[RB][LK];         // 16 KB scores -> probs
  __shared__ float4 ab4s[RB][32];      // {A_dp,B_dp,A_dp+32,B_dp+32}
  __shared__ float4 pvred[4][RB][16];  // PV cross-wave partials
  __shared__ float ovl[RB][DK];        // attention output rows
  __shared__ float red[2][RB][4];      // LN reductions
  const int tid = threadIdx.x;
  // XCD-contiguous swizzle: 512 blocks = 8 XCDs x 64; each XCD sees one batch
  const int swz = (blockIdx.x & 7) * 64 + (blockIdx.x >> 3);
  const int row0 = swz * RB;
  const int batch = row0 >> 10;
  const uint32_t* __restrict__ ekT_b = ekT + (size_t)batch * 32 * LK;
  const float* __restrict__ vp_b = vp + (size_t)batch * LK * DK;

  {
    int r = tid >> 6, d = tid & 63;
    float2 abv = ab_g[(size_t)(row0 + r) * DK + d];
    ((float2*)&ab4s[r][d & 31])[d >> 5] = abv;
  }
  __syncthreads();

  // -------- scores: score_j = C - 2*acc_j (C constant, drops in softmax)
#pragma unroll 1
  for (int jt = 0; jt < LK / 256; ++jt) {
    const int j = (jt << 8) + tid;
    float a0 = 0.f, a1 = 0.f, a2 = 0.f, a3 = 0.f;
#pragma unroll
    for (int dp = 0; dp < 32; ++dp) {
      uint32_t kw = ekT_b[(size_t)dp * LK + j];
      float klo = __uint_as_float(kw << 16);
      float khi = __uint_as_float(kw & 0xffff0000u);
      {
        float4 ab = ab4s[0][dp];
        float x1 = klo + ab.y, x2 = khi + ab.w;
        float num = fmaf(ab.z, x1, ab.x * x2);
        a0 = fmaf(num, __builtin_amdgcn_rcpf(x1 * x2), a0);
      }
      {
        float4 ab = ab4s[1][dp];
        float x1 = klo + ab.y, x2 = khi + ab.w;
        float num = fmaf(ab.z, x1, ab.x * x2);
        a1 = fmaf(num, __builtin_amdgcn_rcpf(x1 * x2), a1);
      }
      {
        float4 ab = ab4s[2][dp];
        float x1 = klo + ab.y, x2 = khi + ab.w;
        float num = fmaf(ab.z, x1, ab.x * x2);
        a2 = fmaf(num, __builtin_amdgcn_rcpf(x1 * x2), a2);
      }
      {
        float4 ab = ab4s[3][dp];
        float x1 = klo + ab.y, x2 = khi + ab.w;
        float num = fmaf(ab.z, x1, ab.x * x2);
        a3 = fmaf(num, __builtin_amdgcn_rcpf(x1 * x2), a3);
      }
    }
    sc[0][j] = a0; sc[1][j] = a1; sc[2][j] = a2; sc[3][j] = a3;
  }
  __syncthreads();

  const int wvv = __builtin_amdgcn_readfirstlane(tid >> 6);
  const int lane = tid & 63;

  // -------- softmax over score = C - 2*acc -> shift by min(acc); wave = row
  {
    const int r = wvv;
    float m = 1e30f;
#pragma unroll
    for (int i = 0; i < 16; ++i) m = fminf(m, sc[r][i * 64 + lane]);
#pragma unroll
    for (int off = 32; off > 0; off >>= 1) m = fminf(m, __shfl_xor(m, off));
    float p[16];
    float ssum = 0.f;
#pragma unroll
    for (int i = 0; i < 16; ++i) {
      float e = __builtin_amdgcn_exp2f((m - sc[r][i * 64 + lane]) * L2E2);
      p[i] = e;
      ssum += e;
    }
#pragma unroll
    for (int off = 32; off > 0; off >>= 1) ssum += __shfl_xor(ssum, off);
    float inv = __builtin_amdgcn_rcpf(ssum);
    float* __restrict__ arow = attn_out + (size_t)(row0 + r) * LK;
#pragma unroll
    for (int i = 0; i < 16; ++i) {
      float pn = p[i] * inv;
      sc[r][i * 64 + lane] = pn;  // keep for PV
      arow[i * 64 + lane] = pn;
    }
  }
  __syncthreads();

  // -------- PV: wave owns 256-j slice; vp read once per block per j
  {
    const int jj = lane >> 4, l16 = lane & 15;
    const float4* __restrict__ vp4 = (const float4*)vp_b;
    float4 a[RB];
#pragma unroll
    for (int r = 0; r < RB; ++r) a[r] = make_float4(0.f, 0.f, 0.f, 0.f);
#pragma unroll 4
    for (int it = 0; it < 64; ++it) {
      int j = (wvv << 8) + (it << 2) + jj;
      float4 vv = vp4[(size_t)j * (DK / 4) + l16];
#pragma unroll
      for (int r = 0; r < RB; ++r) {
        float pw = sc[r][j];
        a[r].x = fmaf(pw, vv.x, a[r].x);
        a[r].y = fmaf(pw, vv.y, a[r].y);
        a[r].z = fmaf(pw, vv.z, a[r].z);
        a[r].w = fmaf(pw, vv.w, a[r].w);
      }
    }
#pragma unroll
    for (int r = 0; r < RB; ++r) {
      a[r].x += __shfl_xor(a[r].x, 16); a[r].y += __shfl_xor(a[r].y, 16);
      a[r].z += __shfl_xor(a[r].z, 16); a[r].w += __shfl_xor(a[r].w, 16);
      a[r].x += __shfl_xor(a[r].x, 32); a[r].y += __shfl_xor(a[r].y, 32);
      a[r].z += __shfl_xor(a[r].z, 32); a[r].w += __shfl_xor(a[r].w, 32);
    }
    if (jj == 0) {
#pragma unroll
      for (int r = 0; r < RB; ++r) pvred[wvv][r][l16] = a[r];
    }
  }
  __syncthreads();
  if (tid < 64) {
    int r = tid >> 4, l16 = tid & 15;
    float4 s = make_float4(0.f, 0.f, 0.f, 0.f);
#pragma unroll
    for (int w = 0; w < 4; ++w) {
      float4 t = pvred[w][r][l16];
      s.x += t.x; s.y += t.y; s.z += t.z; s.w += t.w;
    }
    ((float4*)ovl[r])[l16] = s;
  }
  __syncthreads();

  // -------- FC + residual + LayerNorm tail (rows stay in LDS)
  {
    const int c0 = tid, c1 = tid + 256;
    float y[RB][2];
#pragma unroll
    for (int r = 0; r < RB; ++r) {
      y[r][0] = resid[(size_t)(row0 + r) * D_MODEL + c0];
      y[r][1] = resid[(size_t)(row0 + r) * D_MODEL + c1];
    }
#pragma unroll 4
    for (int e = 0; e < DK; ++e) {
      float w0 = Wfc[(size_t)e * D_MODEL + c0];
      float w1 = Wfc[(size_t)e * D_MODEL + c1];
#pragma unroll
      for (int r = 0; r < RB; ++r) {
        float o = ovl[r][e];
        y[r][0] = fmaf(o, w0, y[r][0]);
        y[r][1] = fmaf(o, w1, y[r][1]);
      }
    }
#pragma unroll
    for (int r = 0; r < RB; ++r) {
      float s = y[r][0] + y[r][1];
#pragma unroll
      for (int off = 32; off > 0; off >>= 1) s += __shfl_xor(s, off);
      if (lane == 0) red[0][r][wvv] = s;
    }
    __syncthreads();
    float mu[RB];
#pragma unroll
    for (int r = 0; r < RB; ++r)
      mu[r] = (red[0][r][0] + red[0][r][1] + red[0][r][2] + red[0][r][3]) *
              (1.0f / D_MODEL);
#pragma unroll
    for (int r = 0; r < RB; ++r) {
      float d0 = y[r][0] - mu[r], d1 = y[r][1] - mu[r];
      float s = d0 * d0 + d1 * d1;
#pragma unroll
      for (int off = 32; off > 0; off >>= 1) s += __shfl_xor(s, off);
      if (lane == 0) red[1][r][wvv] = s;
    }
    __syncthreads();
    float g0 = gamma[c0], g1 = gamma[c1], b0 = beta[c0], b1 = beta[c1];
#pragma unroll
    for (int r = 0; r < RB; ++r) {
      float var = (red[1][r][0] + red[1][r][1] + red[1][r][2] + red[1][r][3]) *
                  (1.0f / D_MODEL);
      float rstd = rsqrtf(var + LN_EPS);
      out[(size_t)(row0 + r) * D_MODEL + c0] = (y[r][0] - mu[r]) * rstd * g0 + b0;
      out[(size_t)(row0 + r) * D_MODEL + c1] = (y[r][1] - mu[r]) * rstd * g1 + b1;
    }
  }
}

extern "C" void kernel_launch(void* const* d_in, const int* in_sizes, int n_in,
                              void* d_out, int out_size, void* d_ws,
                              size_t ws_size, hipStream_t stream) {
  const float* q = (const float*)d_in[0];
  const float* k = (const float*)d_in[1];
  const float* v = (const float*)d_in[2];
  const float* Wq = (const float*)d_in[3];
  const float* Wk = (const float*)d_in[4];
  const float* Wv = (const float*)d_in[5];
  const float* v_param = (const float*)d_in[6];
  const float* Wfc = (const float*)d_in[7];
  const float* gamma = (const float*)d_in[8];
  const float* beta = (const float*)d_in[9];

  float* out = (float*)d_out;                     // [B*LQ*D_MODEL]
  float* attn = out + (size_t)NB * LQ * D_MODEL;  // [B*LQ*LK]

  float* base = (float*)d_ws;
  float2* ab_g = (float2*)base;                      // [2048*64] float2
  uint32_t* ekT = (uint32_t*)(base + (size_t)2 * NB * LQ * DK);  // [2*32*1024]
  float* vp = base + (size_t)2 * NB * LQ * DK + NB * 32 * LK;    // [2048*64]

  hipLaunchKernelGGL(proj_kernel, dim3(3 * 128), dim3(512), 0, stream, q, k, v,
                     Wq, Wk, Wv, v_param, ab_g, ekT, vp);
  hipLaunchKernelGGL(attn_kernel, dim3(NB * LQ / RB), dim3(256), 0, stream,
                     ab_g, ekT, vp, q, Wfc, gamma, beta, out, attn);
}

// Round 7
// 64.916 us; speedup vs baseline: 7.4085x; 2.2778x over previous
//
#include <hip/hip_runtime.h>
#include <cstddef>
#include <cstdint>

#define D_MODEL 512
#define DK 64
#define LQ 1024
#define LK 1024
#define NB 2
#define LN_EPS 1e-6f
#define L2E2 2.8853900817779268f  // 2*log2(e)

// pack two floats to bf16x2 (RNE), low word = a
__device__ __forceinline__ uint32_t pack_bf2(float a, float b) {
  uint32_t ua = __float_as_uint(a), ub = __float_as_uint(b);
  ua = (ua + 0x7fffu + ((ua >> 16) & 1u)) >> 16;
  ub = (ub + 0x7fffu + ((ub >> 16) & 1u)) >> 16;
  return (ub << 16) | ua;
}

// ---------------- projections ----------------
// type 0: qp=q@Wq -> ab_g[row][d] = {v_d*e^{-2qp}, e^{-2qp}}
// type 1: ek=e^{2*(k@Wk)} -> ekT[batch][dp][j] u32 = bf16{ek[dp], ek[dp+32]}
// type 2: vp = v@Wv (f32 row-major)
// 512 thr (8 waves), 32 rows/block (4 rows/wave), grid 3*64=192.
// Rows staged in LDS (float4); W read per-lane from global (L1/L2-resident),
// each W value feeds 4 rows.
#define PR_ROWS 32
__global__ __launch_bounds__(512) void proj_kernel(
    const float* __restrict__ q, const float* __restrict__ k,
    const float* __restrict__ v, const float* __restrict__ Wq,
    const float* __restrict__ Wk, const float* __restrict__ Wv,
    const float* __restrict__ v_param, float2* __restrict__ ab_g,
    uint32_t* __restrict__ ekT, float* __restrict__ vp) {
  __shared__ float rows[PR_ROWS][D_MODEL];  // 64 KB
  const int tid = threadIdx.x;
  const int type = blockIdx.x >> 6;  // 64 row-groups per type
  const int r0 = (blockIdx.x & 63) * PR_ROWS;
  const float* __restrict__ in = (type == 0) ? q : (type == 1) ? k : v;
  const float* __restrict__ W = (type == 0) ? Wq : (type == 1) ? Wk : Wv;
  {
    const float4* __restrict__ in4 = (const float4*)(in + (size_t)r0 * D_MODEL);
    float4* r4 = (float4*)&rows[0][0];
#pragma unroll
    for (int t = 0; t < 8; ++t) r4[tid + 512 * t] = in4[tid + 512 * t];
  }
  __syncthreads();
  const int lane = tid & 63;
  const int wv = tid >> 6;        // 0..7
  const int rglob = r0 + wv * 4;  // this wave's first global row
  const float* __restrict__ Wl = W + lane;
  float c0[4] = {0.f, 0.f, 0.f, 0.f}, c1[4] = {0.f, 0.f, 0.f, 0.f};
#pragma unroll 2
  for (int e = 0; e < D_MODEL; e += 4) {
    float w0 = Wl[(size_t)(e + 0) * DK];
    float w1 = Wl[(size_t)(e + 1) * DK];
    float w2 = Wl[(size_t)(e + 2) * DK];
    float w3 = Wl[(size_t)(e + 3) * DK];
#pragma unroll
    for (int r = 0; r < 4; ++r) {
      float4 x = *(const float4*)&rows[wv * 4 + r][e];
      c0[r] = fmaf(x.x, w0, c0[r]);
      c1[r] = fmaf(x.y, w1, c1[r]);
      c0[r] = fmaf(x.z, w2, c0[r]);
      c1[r] = fmaf(x.w, w3, c1[r]);
    }
  }
  float acc[4];
#pragma unroll
  for (int r = 0; r < 4; ++r) acc[r] = c0[r] + c1[r];
  if (type == 0) {
    float vpar = v_param[lane];
#pragma unroll
    for (int r = 0; r < 4; ++r) {
      float iv = __builtin_amdgcn_exp2f(-L2E2 * acc[r]);
      ab_g[(size_t)(rglob + r) * DK + lane] = make_float2(vpar * iv, iv);
    }
  } else if (type == 1) {
    float e4[4], h4[4];
#pragma unroll
    for (int r = 0; r < 4; ++r) {
      e4[r] = __builtin_amdgcn_exp2f(L2E2 * acc[r]);
      h4[r] = __shfl_down(e4[r], 32);  // lane d gets Ek[d+32]
    }
    if (lane < 32) {
      int b = rglob >> 10, j0 = rglob & 1023;  // rglob%4==0 -> 16B aligned
      uint4 pk;
      pk.x = pack_bf2(e4[0], h4[0]);
      pk.y = pack_bf2(e4[1], h4[1]);
      pk.z = pack_bf2(e4[2], h4[2]);
      pk.w = pack_bf2(e4[3], h4[3]);
      *(uint4*)&ekT[(size_t)b * 32 * LK + (size_t)lane * LK + j0] = pk;
    }
  } else {
#pragma unroll
    for (int r = 0; r < 4; ++r)
      vp[(size_t)(rglob + r) * DK + lane] = acc[r];
  }
}

// ---------------- fused scores + softmax + PV + FC + LN ----------------
// 1024 thr (16 waves), RB=8 rows/block, grid 256 (1 block/CU, 16 waves/CU).
// Thread owns j = tid (whole LK in one pass). K read from L2-resident ekT
// (coalesced dword per dp); each element serves 8 rows.
#define RB 8
__global__ __launch_bounds__(1024, 4) void attn_kernel(
    const float2* __restrict__ ab_g, const uint32_t* __restrict__ ekT,
    const float* __restrict__ vp, const float* __restrict__ resid,
    const float* __restrict__ Wfc, const float* __restrict__ gamma,
    const float* __restrict__ beta, float* __restrict__ out,
    float* __restrict__ attn_out) {
  __shared__ float sc[RB][LK];                        // 32 KB scores -> probs
  __shared__ float4 ab4s[RB][32];                     // 4 KB {A,B,A',B'}
  __shared__ float4 pvred[16][RB][16];                // 32 KB PV partials
  __shared__ __align__(16) float ovlT[DK][RB];        // 2 KB, e-major
  __shared__ float mred[RB][2], sred[RB][2];
  __shared__ float red[2][RB][8];
  const int tid = threadIdx.x;
  const int row0 = blockIdx.x * RB;  // RB | LQ -> single batch per block
  const int batch = row0 >> 10;
  const uint32_t* __restrict__ ekT_b = ekT + (size_t)batch * 32 * LK;
  const float* __restrict__ vp_b = vp + (size_t)batch * LK * DK;

  if (tid < RB * 64) {
    int r = tid >> 6, d = tid & 63;
    float2 abv = ab_g[(size_t)(row0 + r) * DK + d];
    ((float2*)&ab4s[r][d & 31])[d >> 5] = abv;
  }
  __syncthreads();

  // -------- scores: score_j = C - 2*acc_j (C drops in softmax); j = tid
  {
    const int j = tid;
    float acc[RB];
#pragma unroll
    for (int r = 0; r < RB; ++r) acc[r] = 0.f;
#pragma unroll 4
    for (int dp = 0; dp < 32; ++dp) {
      uint32_t kw = ekT_b[(size_t)dp * LK + j];
      float klo = __uint_as_float(kw << 16);
      float khi = __uint_as_float(kw & 0xffff0000u);
#pragma unroll
      for (int r = 0; r < RB; ++r) {
        float4 ab = ab4s[r][dp];
        float x1 = klo + ab.y, x2 = khi + ab.w;
        float num = fmaf(ab.z, x1, ab.x * x2);
        acc[r] = fmaf(num, __builtin_amdgcn_rcpf(x1 * x2), acc[r]);
      }
    }
#pragma unroll
    for (int r = 0; r < RB; ++r) sc[r][j] = acc[r];
  }
  __syncthreads();

  const int wave = __builtin_amdgcn_readfirstlane(tid >> 6);
  const int lane = tid & 63;

  // -------- softmax: 2 waves per row (wave = 2*row + half), shift by min
  {
    const int row = wave >> 1, half = wave & 1;
    const int jb = half * 512;
    float m = 1e30f;
#pragma unroll
    for (int i = 0; i < 8; ++i) m = fminf(m, sc[row][jb + i * 64 + lane]);
#pragma unroll
    for (int off = 32; off > 0; off >>= 1) m = fminf(m, __shfl_xor(m, off));
    if (lane == 0) mred[row][half] = m;
    __syncthreads();
    m = fminf(mred[row][0], mred[row][1]);
    float p[8];
    float ssum = 0.f;
#pragma unroll
    for (int i = 0; i < 8; ++i) {
      float e = __builtin_amdgcn_exp2f((m - sc[row][jb + i * 64 + lane]) * L2E2);
      p[i] = e;
      ssum += e;
    }
#pragma unroll
    for (int off = 32; off > 0; off >>= 1) ssum += __shfl_xor(ssum, off);
    if (lane == 0) sred[row][half] = ssum;
    __syncthreads();
    float inv = __builtin_amdgcn_rcpf(sred[row][0] + sred[row][1]);
    float* __restrict__ arow = attn_out + (size_t)(row0 + row) * LK;
#pragma unroll
    for (int i = 0; i < 8; ++i) {
      float pn = p[i] * inv;
      sc[row][jb + i * 64 + lane] = pn;  // keep for PV
      arow[jb + i * 64 + lane] = pn;
    }
  }
  __syncthreads();

  // -------- PV: wave owns 64-j slice; vp read ONCE per block per j
  {
    const int jj = lane >> 4, l16 = lane & 15;
    const float4* __restrict__ vp4 = (const float4*)vp_b;
    float4 a[RB];
#pragma unroll
    for (int r = 0; r < RB; ++r) a[r] = make_float4(0.f, 0.f, 0.f, 0.f);
#pragma unroll 2
    for (int it = 0; it < 16; ++it) {
      int j = (wave << 6) + (it << 2) + jj;
      float4 vv = vp4[(size_t)j * (DK / 4) + l16];
#pragma unroll
      for (int r = 0; r < RB; ++r) {
        float pw = sc[r][j];
        a[r].x = fmaf(pw, vv.x, a[r].x);
        a[r].y = fmaf(pw, vv.y, a[r].y);
        a[r].z = fmaf(pw, vv.z, a[r].z);
        a[r].w = fmaf(pw, vv.w, a[r].w);
      }
    }
#pragma unroll
    for (int r = 0; r < RB; ++r) {
      a[r].x += __shfl_xor(a[r].x, 16); a[r].y += __shfl_xor(a[r].y, 16);
      a[r].z += __shfl_xor(a[r].z, 16); a[r].w += __shfl_xor(a[r].w, 16);
      a[r].x += __shfl_xor(a[r].x, 32); a[r].y += __shfl_xor(a[r].y, 32);
      a[r].z += __shfl_xor(a[r].z, 32); a[r].w += __shfl_xor(a[r].w, 32);
    }
    if (jj == 0) {
#pragma unroll
      for (int r = 0; r < RB; ++r) pvred[wave][r][l16] = a[r];
    }
  }
  __syncthreads();
  if (tid < 128) {  // final PV reduce -> transposed ovlT[e][r]
    int r = tid >> 4, l16 = tid & 15;
    float4 s = make_float4(0.f, 0.f, 0.f, 0.f);
#pragma unroll
    for (int w = 0; w < 16; ++w) {
      float4 t = pvred[w][r][l16];
      s.x += t.x; s.y += t.y; s.z += t.z; s.w += t.w;
    }
    ovlT[l16 * 4 + 0][r] = s.x;
    ovlT[l16 * 4 + 1][r] = s.y;
    ovlT[l16 * 4 + 2][r] = s.z;
    ovlT[l16 * 4 + 3][r] = s.w;
  }
  __syncthreads();

  // -------- FC + residual + LN: group g = tid>>9 owns rows g*4..g*4+3
  {
    const int g = tid >> 9, c = tid & 511, rbase = g * 4;
    const int wv8 = (tid >> 6) & 7;
    float y[4];
#pragma unroll
    for (int rr = 0; rr < 4; ++rr)
      y[rr] = resid[(size_t)(row0 + rbase + rr) * D_MODEL + c];
#pragma unroll 4
    for (int e = 0; e < DK; ++e) {
      float w = Wfc[(size_t)e * D_MODEL + c];
      float4 ov = *(const float4*)&ovlT[e][rbase];
      y[0] = fmaf(ov.x, w, y[0]);
      y[1] = fmaf(ov.y, w, y[1]);
      y[2] = fmaf(ov.z, w, y[2]);
      y[3] = fmaf(ov.w, w, y[3]);
    }
#pragma unroll
    for (int rr = 0; rr < 4; ++rr) {
      float s = y[rr];
#pragma unroll
      for (int off = 32; off > 0; off >>= 1) s += __shfl_xor(s, off);
      if (lane == 0) red[0][rbase + rr][wv8] = s;
    }
    __syncthreads();
    float mu[4];
#pragma unroll
    for (int rr = 0; rr < 4; ++rr) {
      float s = 0.f;
#pragma unroll
      for (int w = 0; w < 8; ++w) s += red[0][rbase + rr][w];
      mu[rr] = s * (1.0f / D_MODEL);
    }
#pragma unroll
    for (int rr = 0; rr < 4; ++rr) {
      float d = y[rr] - mu[rr];
      float s = d * d;
#pragma unroll
      for (int off = 32; off > 0; off >>= 1) s += __shfl_xor(s, off);
      if (lane == 0) red[1][rbase + rr][wv8] = s;
    }
    __syncthreads();
    float gg = gamma[c], bb = beta[c];
#pragma unroll
    for (int rr = 0; rr < 4; ++rr) {
      float s = 0.f;
#pragma unroll
      for (int w = 0; w < 8; ++w) s += red[1][rbase + rr][w];
      float var = s * (1.0f / D_MODEL);
      float rstd = rsqrtf(var + LN_EPS);
      out[(size_t)(row0 + rbase + rr) * D_MODEL + c] =
          (y[rr] - mu[rr]) * rstd * gg + bb;
    }
  }
}

extern "C" void kernel_launch(void* const* d_in, const int* in_sizes, int n_in,
                              void* d_out, int out_size, void* d_ws,
                              size_t ws_size, hipStream_t stream) {
  const float* q = (const float*)d_in[0];
  const float* k = (const float*)d_in[1];
  const float* v = (const float*)d_in[2];
  const float* Wq = (const float*)d_in[3];
  const float* Wk = (const float*)d_in[4];
  const float* Wv = (const float*)d_in[5];
  const float* v_param = (const float*)d_in[6];
  const float* Wfc = (const float*)d_in[7];
  const float* gamma = (const float*)d_in[8];
  const float* beta = (const float*)d_in[9];

  float* out = (float*)d_out;                     // [B*LQ*D_MODEL]
  float* attn = out + (size_t)NB * LQ * D_MODEL;  // [B*LQ*LK]

  float* base = (float*)d_ws;
  float2* ab_g = (float2*)base;                                  // [2048*64]
  uint32_t* ekT = (uint32_t*)(base + (size_t)2 * NB * LQ * DK);  // [2*32*1024]
  float* vp = base + (size_t)2 * NB * LQ * DK + NB * 32 * LK;    // [2048*64]

  hipLaunchKernelGGL(proj_kernel, dim3(3 * 64), dim3(512), 0, stream, q, k, v,
                     Wq, Wk, Wv, v_param, ab_g, ekT, vp);
  hipLaunchKernelGGL(attn_kernel, dim3(NB * LQ / RB), dim3(1024), 0, stream,
                     ab_g, ekT, vp, q, Wfc, gamma, beta, out, attn);
}

// Round 8
// 60.111 us; speedup vs baseline: 8.0007x; 1.0799x over previous
//
#include <hip/hip_runtime.h>
#include <cstddef>
#include <cstdint>

#define D_MODEL 512
#define DK 64
#define LQ 1024
#define LK 1024
#define NB 2
#define LN_EPS 1e-6f
#define L2E2 2.8853900817779268f  // 2*log2(e)

// pack two floats to bf16x2 (RNE), low word = a
__device__ __forceinline__ uint32_t pack_bf2(float a, float b) {
  uint32_t ua = __float_as_uint(a), ub = __float_as_uint(b);
  ua = (ua + 0x7fffu + ((ua >> 16) & 1u)) >> 16;
  ub = (ub + 0x7fffu + ((ub >> 16) & 1u)) >> 16;
  return (ub << 16) | ua;
}

// ---------------- projections ----------------
// type 0: qp=q@Wq -> ab_g[row][d] = {v_d*e^{-2qp}, e^{-2qp}}
// type 1: ek=e^{2*(k@Wk)} -> ekT[batch][dp][j] u32 = bf16{ek[dp], ek[dp+32]}
// type 2: vp = v@Wv (f32 row-major)
// 256 thr (4 waves), 8 rows/block (2 rows/wave), grid 3*256=768 (3 blocks/CU).
// Rows staged in LDS (b128 broadcast); W read per-lane coalesced (L1/L2).
#define PR_ROWS 8
__global__ __launch_bounds__(256, 4) void proj_kernel(
    const float* __restrict__ q, const float* __restrict__ k,
    const float* __restrict__ v, const float* __restrict__ Wq,
    const float* __restrict__ Wk, const float* __restrict__ Wv,
    const float* __restrict__ v_param, float2* __restrict__ ab_g,
    uint32_t* __restrict__ ekT, float* __restrict__ vp) {
  __shared__ float rows[PR_ROWS][D_MODEL];  // 16 KB
  const int tid = threadIdx.x;
  const int type = blockIdx.x >> 8;  // 256 row-groups per type
  const int r0 = (blockIdx.x & 255) * PR_ROWS;
  const float* __restrict__ in = (type == 0) ? q : (type == 1) ? k : v;
  const float* __restrict__ W = (type == 0) ? Wq : (type == 1) ? Wk : Wv;
  {
    const float4* __restrict__ in4 = (const float4*)(in + (size_t)r0 * D_MODEL);
    float4* r4 = (float4*)&rows[0][0];
#pragma unroll
    for (int t = 0; t < 4; ++t) r4[tid + 256 * t] = in4[tid + 256 * t];
  }
  __syncthreads();
  const int lane = tid & 63;
  const int wv = tid >> 6;        // 0..3
  const int rglob = r0 + wv * 2;  // this wave's first global row (even)
  const float* __restrict__ Wl = W + lane;
  const float* __restrict__ rA = rows[wv * 2];
  const float* __restrict__ rB = rows[wv * 2 + 1];
  float c0a = 0.f, c1a = 0.f, c0b = 0.f, c1b = 0.f;
#pragma unroll 2
  for (int e = 0; e < D_MODEL; e += 4) {
    float w0 = Wl[(size_t)(e + 0) * DK];
    float w1 = Wl[(size_t)(e + 1) * DK];
    float w2 = Wl[(size_t)(e + 2) * DK];
    float w3 = Wl[(size_t)(e + 3) * DK];
    float4 xa = *(const float4*)&rA[e];
    float4 xb = *(const float4*)&rB[e];
    c0a = fmaf(xa.x, w0, c0a); c1a = fmaf(xa.y, w1, c1a);
    c0a = fmaf(xa.z, w2, c0a); c1a = fmaf(xa.w, w3, c1a);
    c0b = fmaf(xb.x, w0, c0b); c1b = fmaf(xb.y, w1, c1b);
    c0b = fmaf(xb.z, w2, c0b); c1b = fmaf(xb.w, w3, c1b);
  }
  float acc0 = c0a + c1a, acc1 = c0b + c1b;
  if (type == 0) {
    float vpar = v_param[lane];
    float i0 = __builtin_amdgcn_exp2f(-L2E2 * acc0);
    float i1 = __builtin_amdgcn_exp2f(-L2E2 * acc1);
    ab_g[(size_t)(rglob + 0) * DK + lane] = make_float2(vpar * i0, i0);
    ab_g[(size_t)(rglob + 1) * DK + lane] = make_float2(vpar * i1, i1);
  } else if (type == 1) {
    float e0 = __builtin_amdgcn_exp2f(L2E2 * acc0);
    float e1 = __builtin_amdgcn_exp2f(L2E2 * acc1);
    float h0 = __shfl_down(e0, 32);  // lane d gets Ek[d+32]
    float h1 = __shfl_down(e1, 32);
    if (lane < 32) {
      int b = rglob >> 10, j0 = rglob & 1023;  // rglob even -> 8B aligned
      uint2 pk;
      pk.x = pack_bf2(e0, h0);
      pk.y = pack_bf2(e1, h1);
      *(uint2*)&ekT[(size_t)b * 32 * LK + (size_t)lane * LK + j0] = pk;
    }
  } else {
    vp[(size_t)(rglob + 0) * DK + lane] = acc0;
    vp[(size_t)(rglob + 1) * DK + lane] = acc1;
  }
}

// ---------------- fused scores + softmax + PV + FC + LN ----------------
// 512 thr (8 waves), RB=8 rows/block, grid 256, 2 blocks/CU (LDS ~56KB).
// Thread owns TWO j columns (tid, tid+512): each ab4s b128 broadcast serves
// 2 j -> total LDS broadcast traffic halves (round-7 bottleneck).
#define RB 8
__global__ __launch_bounds__(512, 4) void attn_kernel(
    const float2* __restrict__ ab_g, const uint32_t* __restrict__ ekT,
    const float* __restrict__ vp, const float* __restrict__ resid,
    const float* __restrict__ Wfc, const float* __restrict__ gamma,
    const float* __restrict__ beta, float* __restrict__ out,
    float* __restrict__ attn_out) {
  __shared__ float sc[RB][LK];                  // 32 KB scores -> probs
  __shared__ float4 ab4s[RB][32];               // 4 KB {A,B,A',B'}
  __shared__ float4 pvred[8][RB][16];           // 16 KB PV partials
  __shared__ __align__(16) float ovlT[DK][RB];  // 2 KB, e-major
  __shared__ float red[2][RB][8];               // LN reductions
  const int tid = threadIdx.x;
  const int row0 = blockIdx.x * RB;  // RB | LQ -> single batch per block
  const int batch = row0 >> 10;
  const uint32_t* __restrict__ ekT_b = ekT + (size_t)batch * 32 * LK;
  const float* __restrict__ vp_b = vp + (size_t)batch * LK * DK;

  {
    int r = tid >> 6, d = tid & 63;
    float2 abv = ab_g[(size_t)(row0 + r) * DK + d];
    ((float2*)&ab4s[r][d & 31])[d >> 5] = abv;
  }
  __syncthreads();

  // -------- scores: score_j = C - 2*acc_j (C drops in softmax)
  // thread's j0 = tid, j1 = tid + 512
  {
    float acc0[RB], acc1[RB];
#pragma unroll
    for (int r = 0; r < RB; ++r) { acc0[r] = 0.f; acc1[r] = 0.f; }
#pragma unroll 4
    for (int dp = 0; dp < 32; ++dp) {
      uint32_t kw0 = ekT_b[(size_t)dp * LK + tid];
      uint32_t kw1 = ekT_b[(size_t)dp * LK + tid + 512];
      float klo0 = __uint_as_float(kw0 << 16);
      float khi0 = __uint_as_float(kw0 & 0xffff0000u);
      float klo1 = __uint_as_float(kw1 << 16);
      float khi1 = __uint_as_float(kw1 & 0xffff0000u);
#pragma unroll
      for (int r = 0; r < RB; ++r) {
        float4 ab = ab4s[r][dp];  // one broadcast serves both j
        float x1 = klo0 + ab.y, x2 = khi0 + ab.w;
        float n0 = fmaf(ab.z, x1, ab.x * x2);
        acc0[r] = fmaf(n0, __builtin_amdgcn_rcpf(x1 * x2), acc0[r]);
        float y1 = klo1 + ab.y, y2 = khi1 + ab.w;
        float n1 = fmaf(ab.z, y1, ab.x * y2);
        acc1[r] = fmaf(n1, __builtin_amdgcn_rcpf(y1 * y2), acc1[r]);
      }
    }
#pragma unroll
    for (int r = 0; r < RB; ++r) {
      sc[r][tid] = acc0[r];
      sc[r][tid + 512] = acc1[r];
    }
  }
  __syncthreads();

  const int wave = __builtin_amdgcn_readfirstlane(tid >> 6);
  const int lane = tid & 63;

  // -------- softmax: wave = row (8 waves, 8 rows), shift by min(acc)
  {
    const int r = wave;
    float m = 1e30f;
#pragma unroll
    for (int i = 0; i < 16; ++i) m = fminf(m, sc[r][i * 64 + lane]);
#pragma unroll
    for (int off = 32; off > 0; off >>= 1) m = fminf(m, __shfl_xor(m, off));
    float p[16];
    float ssum = 0.f;
#pragma unroll
    for (int i = 0; i < 16; ++i) {
      float e = __builtin_amdgcn_exp2f((m - sc[r][i * 64 + lane]) * L2E2);
      p[i] = e;
      ssum += e;
    }
#pragma unroll
    for (int off = 32; off > 0; off >>= 1) ssum += __shfl_xor(ssum, off);
    float inv = __builtin_amdgcn_rcpf(ssum);
    float* __restrict__ arow = attn_out + (size_t)(row0 + r) * LK;
#pragma unroll
    for (int i = 0; i < 16; ++i) {
      float pn = p[i] * inv;
      sc[r][i * 64 + lane] = pn;  // keep for PV
      arow[i * 64 + lane] = pn;
    }
  }
  __syncthreads();

  // -------- PV: wave owns 128-j slice; vp read once per block per j
  {
    const int jj = lane >> 4, l16 = lane & 15;
    const float4* __restrict__ vp4 = (const float4*)vp_b;
    float4 a[RB];
#pragma unroll
    for (int r = 0; r < RB; ++r) a[r] = make_float4(0.f, 0.f, 0.f, 0.f);
#pragma unroll 2
    for (int it = 0; it < 32; ++it) {
      int j = (wave << 7) + (it << 2) + jj;
      float4 vv = vp4[(size_t)j * (DK / 4) + l16];
#pragma unroll
      for (int r = 0; r < RB; ++r) {
        float pw = sc[r][j];
        a[r].x = fmaf(pw, vv.x, a[r].x);
        a[r].y = fmaf(pw, vv.y, a[r].y);
        a[r].z = fmaf(pw, vv.z, a[r].z);
        a[r].w = fmaf(pw, vv.w, a[r].w);
      }
    }
#pragma unroll
    for (int r = 0; r < RB; ++r) {
      a[r].x += __shfl_xor(a[r].x, 16); a[r].y += __shfl_xor(a[r].y, 16);
      a[r].z += __shfl_xor(a[r].z, 16); a[r].w += __shfl_xor(a[r].w, 16);
      a[r].x += __shfl_xor(a[r].x, 32); a[r].y += __shfl_xor(a[r].y, 32);
      a[r].z += __shfl_xor(a[r].z, 32); a[r].w += __shfl_xor(a[r].w, 32);
    }
    if (jj == 0) {
#pragma unroll
      for (int r = 0; r < RB; ++r) pvred[wave][r][l16] = a[r];
    }
  }
  __syncthreads();
  if (tid < 128) {  // final PV reduce -> transposed ovlT[e][r]
    int r = tid >> 4, l16 = tid & 15;
    float4 s = make_float4(0.f, 0.f, 0.f, 0.f);
#pragma unroll
    for (int w = 0; w < 8; ++w) {
      float4 t = pvred[w][r][l16];
      s.x += t.x; s.y += t.y; s.z += t.z; s.w += t.w;
    }
    ovlT[l16 * 4 + 0][r] = s.x;
    ovlT[l16 * 4 + 1][r] = s.y;
    ovlT[l16 * 4 + 2][r] = s.z;
    ovlT[l16 * 4 + 3][r] = s.w;
  }
  __syncthreads();

  // -------- FC + residual + LN: thread owns column c = tid for all 8 rows
  {
    const int c = tid;
    float y[RB];
#pragma unroll
    for (int r = 0; r < RB; ++r)
      y[r] = resid[(size_t)(row0 + r) * D_MODEL + c];
#pragma unroll 4
    for (int e = 0; e < DK; ++e) {
      float w = Wfc[(size_t)e * D_MODEL + c];
      float4 o0 = *(const float4*)&ovlT[e][0];
      float4 o1 = *(const float4*)&ovlT[e][4];
      y[0] = fmaf(o0.x, w, y[0]); y[1] = fmaf(o0.y, w, y[1]);
      y[2] = fmaf(o0.z, w, y[2]); y[3] = fmaf(o0.w, w, y[3]);
      y[4] = fmaf(o1.x, w, y[4]); y[5] = fmaf(o1.y, w, y[5]);
      y[6] = fmaf(o1.z, w, y[6]); y[7] = fmaf(o1.w, w, y[7]);
    }
#pragma unroll
    for (int r = 0; r < RB; ++r) {
      float s = y[r];
#pragma unroll
      for (int off = 32; off > 0; off >>= 1) s += __shfl_xor(s, off);
      if (lane == 0) red[0][r][wave] = s;
    }
    __syncthreads();
    float mu[RB];
#pragma unroll
    for (int r = 0; r < RB; ++r) {
      float s = 0.f;
#pragma unroll
      for (int w = 0; w < 8; ++w) s += red[0][r][w];
      mu[r] = s * (1.0f / D_MODEL);
    }
#pragma unroll
    for (int r = 0; r < RB; ++r) {
      float d = y[r] - mu[r];
      float s = d * d;
#pragma unroll
      for (int off = 32; off > 0; off >>= 1) s += __shfl_xor(s, off);
      if (lane == 0) red[1][r][wave] = s;
    }
    __syncthreads();
    float gg = gamma[c], bb = beta[c];
#pragma unroll
    for (int r = 0; r < RB; ++r) {
      float s = 0.f;
#pragma unroll
      for (int w = 0; w < 8; ++w) s += red[1][r][w];
      float var = s * (1.0f / D_MODEL);
      float rstd = rsqrtf(var + LN_EPS);
      out[(size_t)(row0 + r) * D_MODEL + c] = (y[r] - mu[r]) * rstd * gg + bb;
    }
  }
}

extern "C" void kernel_launch(void* const* d_in, const int* in_sizes, int n_in,
                              void* d_out, int out_size, void* d_ws,
                              size_t ws_size, hipStream_t stream) {
  const float* q = (const float*)d_in[0];
  const float* k = (const float*)d_in[1];
  const float* v = (const float*)d_in[2];
  const float* Wq = (const float*)d_in[3];
  const float* Wk = (const float*)d_in[4];
  const float* Wv = (const float*)d_in[5];
  const float* v_param = (const float*)d_in[6];
  const float* Wfc = (const float*)d_in[7];
  const float* gamma = (const float*)d_in[8];
  const float* beta = (const float*)d_in[9];

  float* out = (float*)d_out;                     // [B*LQ*D_MODEL]
  float* attn = out + (size_t)NB * LQ * D_MODEL;  // [B*LQ*LK]

  float* base = (float*)d_ws;
  float2* ab_g = (float2*)base;                                  // [2048*64]
  uint32_t* ekT = (uint32_t*)(base + (size_t)2 * NB * LQ * DK);  // [2*32*1024]
  float* vp = base + (size_t)2 * NB * LQ * DK + NB * 32 * LK;    // [2048*64]

  hipLaunchKernelGGL(proj_kernel, dim3(3 * 256), dim3(256), 0, stream, q, k, v,
                     Wq, Wk, Wv, v_param, ab_g, ekT, vp);
  hipLaunchKernelGGL(attn_kernel, dim3(NB * LQ / RB), dim3(512), 0, stream,
                     ab_g, ekT, vp, q, Wfc, gamma, beta, out, attn);
}